// Round 4
// baseline (221.831 us; speedup 1.0000x reference)
//
#include <hip/hip_runtime.h>

#define D 64
#define KP 50          // neighbors per row
#define STR 68         // padded LDS row stride (floats): 17 x 16B -> conflict-free
#define NITEMS 10000   // R row stride

struct SM {
  float X[KP * STR];   // row-major X[k][j]; gate output written in place
  float init_gate[D];  // gate bias
  float init_att[D];   // ba1 + ctx @ Wa1hi
  float ctx[D];
  float a[D];          // softmax weights
  float v[D];          // attention-weighted sum
  float buf0[D];
  float buf1[D];
  float hS[D];
  float cat[2 * D];
  float part[4 * D];   // partials (matvec / att-score / weighted-sum)
  int   ci[KP];
  int   ci2[KP];
  int   rk[KP];
};

// acc[dd] += sum_j Xr[j] * Wp[j*D + dd]   (Wp wave-uniform -> s_load + SGPR FMA)
__device__ inline void mm16(const float* Xr, const float* __restrict__ Wp,
                            float acc[16]) {
  for (int j4 = 0; j4 < D; j4 += 4) {
    float4 xv = *(const float4*)&Xr[j4];
    const float xr[4] = {xv.x, xv.y, xv.z, xv.w};
#pragma unroll
    for (int jj = 0; jj < 4; ++jj) {
#pragma unroll
      for (int dd = 0; dd < 16; ++dd)
        acc[dd] = fmaf(xr[jj], Wp[(j4 + jj) * D + dd], acc[dd]);
    }
  }
}

// X <- relu(init_gate + op[rk[k]] + X @ W), in place. lane = k, wave owns 16 d.
__device__ inline void gate_mm(SM& sm, const float* __restrict__ W,
                               const float* __restrict__ oprow) {
  const int t = threadIdx.x, lane = t & 63;
  const int k = lane < KP ? lane : KP - 1;
  const int dwu = __builtin_amdgcn_readfirstlane((t >> 6) << 4);
  float acc[16];
#pragma unroll
  for (int dd = 0; dd < 16; ++dd) acc[dd] = sm.init_gate[dwu + dd];
  mm16(&sm.X[k * STR], &W[dwu], acc);
  // opinion-row add AFTER the mm: hides the R-gather latency under ~2000 cyc
  {
    const float* op = &oprow[sm.rk[k] * D + dwu];
#pragma unroll
    for (int dd4 = 0; dd4 < 16; dd4 += 4) {
      float4 ov = *(const float4*)&op[dd4];
      acc[dd4 + 0] += ov.x; acc[dd4 + 1] += ov.y;
      acc[dd4 + 2] += ov.z; acc[dd4 + 3] += ov.w;
    }
  }
  __syncthreads();   // all reads of X complete
  if (lane < KP) {
#pragma unroll
    for (int dd4 = 0; dd4 < 16; dd4 += 4) {
      float4 o;
      o.x = fmaxf(acc[dd4 + 0], 0.f);
      o.y = fmaxf(acc[dd4 + 1], 0.f);
      o.z = fmaxf(acc[dd4 + 2], 0.f);
      o.w = fmaxf(acc[dd4 + 3], 0.f);
      *(float4*)&sm.X[k * STR + dwu + dd4] = o;
    }
  }
  __syncthreads();
}

// scores + softmax -> sm.a[k]. h never materialized (ba2 softmax-invariant).
__device__ inline void att_softmax(SM& sm, const float* __restrict__ Wa1,
                                   const float* __restrict__ Wa2) {
  const int t = threadIdx.x, lane = t & 63;
  const int k = lane < KP ? lane : KP - 1;
  const int dwu = __builtin_amdgcn_readfirstlane((t >> 6) << 4);
  float acc[16];
#pragma unroll
  for (int dd = 0; dd < 16; ++dd) acc[dd] = sm.init_att[dwu + dd];
  mm16(&sm.X[k * STR], &Wa1[dwu], acc);
  const float* __restrict__ W2 = &Wa2[dwu];
  float s = 0.f;
#pragma unroll
  for (int dd = 0; dd < 16; ++dd) s = fmaf(fmaxf(acc[dd], 0.f), W2[dd], s);
  sm.part[(t >> 6) * D + lane] = s;
  __syncthreads();
  float val = sm.part[lane] + sm.part[D + lane] + sm.part[2 * D + lane] +
              sm.part[3 * D + lane];
  val = (lane < KP) ? val : -1e30f;
  float m = val;
#pragma unroll
  for (int o = 1; o < 64; o <<= 1) m = fmaxf(m, __shfl_xor(m, o, 64));
  float e = (lane < KP) ? __expf(val - m) : 0.f;
  float ssum = e;
#pragma unroll
  for (int o = 1; o < 64; o <<= 1) ssum += __shfl_xor(ssum, o, 64);
  if (t < D) sm.a[lane] = e / ssum;
  __syncthreads();
}

// v[d] = sum_k a[k] * X[k][d], 256 threads
__device__ inline void weighted_sum(SM& sm) {
  const int t = threadIdx.x;
  const int d = t & 63, kw = t >> 6;
  float p = 0.f;
  for (int k = kw; k < KP; k += 4) p = fmaf(sm.a[k], sm.X[k * STR + d], p);
  sm.part[kw * D + d] = p;
  __syncthreads();
  if (t < D)
    sm.v[t] = sm.part[t] + sm.part[D + t] + sm.part[2 * D + t] +
              sm.part[3 * D + t];
  __syncthreads();
}

// y[d] = act(bias[d] + sum_{j<J} xin[j]*W[j][d]); 256 threads
template <int J, bool RELU>
__device__ inline void mv(SM& sm, const float* xin, float* y,
                          const float* __restrict__ W, const float* bias) {
  const int w = threadIdx.x >> 6, d = threadIdx.x & 63;
  const int JW = J / 4;
  float p = 0.f;
  const float* xw = &xin[w * JW];
  const float* Wp = &W[(w * JW) * D + d];
  for (int j = 0; j < JW; ++j) {
    p = fmaf(xw[j], *Wp, p);
    Wp += D;
  }
  sm.part[w * D + d] = p;
  __syncthreads();
  if (threadIdx.x < D) {
    float s = bias[d] + sm.part[d] + sm.part[D + d] + sm.part[2 * D + d] +
              sm.part[3 * D + d];
    y[d] = RELU ? fmaxf(s, 0.f) : s;
  }
  __syncthreads();
}

// X[k][j] = src[idx[k]*D + j] (coalesced global, conflict-free LDS)
__device__ inline void load_rows(SM& sm, const float* __restrict__ src,
                                 const int* idx) {
  const int j = threadIdx.x & 63, kw = threadIdx.x >> 6;
  for (int k = kw; k < KP; k += 4) sm.X[k * STR + j] = src[idx[k] * D + j];
}

// ---------------- kernel 0: opinion tables op[r] = opinion_emb[r] @ Wg[64:] -----
__global__ __launch_bounds__(64) void k_op(const float* opinion_emb,
                                           const float* ia_Wg, const float* ua_Wg,
                                           float* op_ia, float* op_ua) {
  const int r = blockIdx.x % 5;
  const bool ua = blockIdx.x >= 5;
  const float* Wg = ua ? ua_Wg : ia_Wg;
  float* o = ua ? op_ua : op_ia;
  const int d = threadIdx.x;
  float acc = 0.f;
  for (int j = 0; j < D; ++j)
    acc = fmaf(opinion_emb[r * D + j], Wg[(D + j) * D + d], acc);
  o[r * D + d] = acc;
}

// ---------------- kernel 1: h_I_all for every user ------------------------------
__global__ __launch_bounds__(256, 8) void k_hIall(
    const int* C, const int* Rm, const float* user_emb, const float* item_emb,
    const float* ia_Wg, const float* ia_bg, const float* ia_Wa1,
    const float* ia_ba1, const float* ia_Wa2, const float* ia_W,
    const float* ia_b, const float* op_ia, float* h_I_all) {
  __shared__ SM sm;
  const int u = blockIdx.x;
  const int t = threadIdx.x;
  if (t < KP) sm.ci[t] = C[u * KP + t];
  if (t < D) {
    sm.ctx[t] = user_emb[u * D + t];
    sm.init_gate[t] = ia_bg[t];
  }
  __syncthreads();
  load_rows(sm, item_emb, sm.ci);
  if (t < KP) sm.rk[t] = Rm[u * NITEMS + sm.ci[t]];  // HBM miss; consumed late
  // init_att = ba1 + ctx @ Wa1hi; its internal barriers fence X/rk writes
  mv<D, false>(sm, sm.ctx, sm.init_att, &ia_Wa1[D * D], ia_ba1);
  gate_mm(sm, ia_Wg, op_ia);                          // X <- x rows (in place)
  att_softmax(sm, ia_Wa1, ia_Wa2);
  weighted_sum(sm);
  mv<D, true>(sm, sm.v, sm.buf0, ia_W, ia_b);
  if (t < D) h_I_all[u * D + t] = sm.buf0[t];
}

// ---------------- kernel 2: h_S + z + fu/rp MLPs → output -----------------------
__global__ __launch_bounds__(256, 8) void k_batch(
    const int* user_idx, const int* item_idx, const int* Nn, const int* Bm,
    const int* Rm, const float* user_emb, const float* item_emb,
    const float* sa_Wa1, const float* sa_ba1, const float* sa_Wa2,
    const float* sa_W, const float* sa_b, const float* ua_Wg,
    const float* ua_bg, const float* ua_Wa1, const float* ua_ba1,
    const float* ua_Wa2, const float* ua_W, const float* ua_b,
    const float* op_ua, const float* fu_W1, const float* fu_b1,
    const float* fu_W2, const float* fu_b2, const float* fu_W3,
    const float* fu_b3, const float* rp_W1, const float* rp_b1,
    const float* rp_W2, const float* rp_b2, const float* rp_W3,
    const float* rp_b3, const float* h_I_all, float* out) {
  __shared__ SM sm;
  const int b = blockIdx.x, t = threadIdx.x;
  const int u = user_idx[b];
  const int it = item_idx[b];
  if (t < KP) {
    sm.ci[t] = Nn[u * KP + t];
    sm.ci2[t] = Bm[it * KP + t];
  }
  if (t < D) sm.ctx[t] = user_emb[u * D + t];
  __syncthreads();
  // ---- phase S: social aggregation over h_I_all rows ----
  load_rows(sm, h_I_all, sm.ci);
  if (t < KP) sm.rk[t] = Rm[sm.ci2[t] * NITEMS + it];  // prefetch for phase Z
  mv<D, false>(sm, sm.ctx, sm.init_att, &sa_Wa1[D * D], sa_ba1);
  att_softmax(sm, sa_Wa1, sa_Wa2);
  weighted_sum(sm);
  mv<D, true>(sm, sm.v, sm.hS, sa_W, sa_b);
  // ---- phase Z: item-side aggregation ----
  if (t < D) {
    sm.ctx[t] = item_emb[it * D + t];
    sm.init_gate[t] = ua_bg[t];
  }
  __syncthreads();
  load_rows(sm, user_emb, sm.ci2);
  mv<D, false>(sm, sm.ctx, sm.init_att, &ua_Wa1[D * D], ua_ba1);
  gate_mm(sm, ua_Wg, op_ua);                          // X <- f rows
  att_softmax(sm, ua_Wa1, ua_Wa2);
  weighted_sum(sm);
  mv<D, true>(sm, sm.v, sm.buf1, ua_W, ua_b);         // z in buf1
  // ---- fu MLP on concat(h_I_all[u], h_S) ----
  if (t < D) {
    sm.cat[t] = h_I_all[u * D + t];
    sm.cat[D + t] = sm.hS[t];
  }
  __syncthreads();
  mv<2 * D, true>(sm, sm.cat, sm.buf0, fu_W1, fu_b1);
  mv<D, true>(sm, sm.buf0, sm.v, fu_W2, fu_b2);
  mv<D, true>(sm, sm.v, sm.buf0, fu_W3, fu_b3);
  // ---- rp MLP on concat(h, z) ----
  if (t < D) {
    sm.cat[t] = sm.buf0[t];
    sm.cat[D + t] = sm.buf1[t];
  }
  __syncthreads();
  mv<2 * D, true>(sm, sm.cat, sm.buf0, rp_W1, rp_b1);
  mv<D, true>(sm, sm.buf0, sm.v, rp_W2, rp_b2);
  if (t < D) {
    float p = sm.v[t] * rp_W3[t];
#pragma unroll
    for (int o = 1; o < 64; o <<= 1) p += __shfl_xor(p, o, 64);
    if (t == 0) out[b] = p + rp_b3[0];
  }
}

extern "C" void kernel_launch(void* const* d_in, const int* in_sizes, int n_in,
                              void* d_out, int out_size, void* d_ws,
                              size_t ws_size, hipStream_t stream) {
  const int* user_idx = (const int*)d_in[0];
  const int* item_idx = (const int*)d_in[1];
  const int* C = (const int*)d_in[2];
  const int* Nn = (const int*)d_in[3];
  const int* Bm = (const int*)d_in[4];
  const int* Rm = (const int*)d_in[5];
  const float* user_emb = (const float*)d_in[6];
  const float* item_emb = (const float*)d_in[7];
  const float* opinion_emb = (const float*)d_in[8];
  const float* ia_Wg = (const float*)d_in[9];
  const float* ia_bg = (const float*)d_in[10];
  const float* ua_Wg = (const float*)d_in[11];
  const float* ua_bg = (const float*)d_in[12];
  const float* ia_Wa1 = (const float*)d_in[13];
  const float* ia_ba1 = (const float*)d_in[14];
  const float* ia_Wa2 = (const float*)d_in[15];
  const float* ia_W = (const float*)d_in[17];
  const float* ia_b = (const float*)d_in[18];
  const float* sa_Wa1 = (const float*)d_in[19];
  const float* sa_ba1 = (const float*)d_in[20];
  const float* sa_Wa2 = (const float*)d_in[21];
  const float* sa_W = (const float*)d_in[23];
  const float* sa_b = (const float*)d_in[24];
  const float* ua_Wa1 = (const float*)d_in[25];
  const float* ua_ba1 = (const float*)d_in[26];
  const float* ua_Wa2 = (const float*)d_in[27];
  const float* ua_W = (const float*)d_in[29];
  const float* ua_b = (const float*)d_in[30];
  const float* fu_W1 = (const float*)d_in[31];
  const float* fu_b1 = (const float*)d_in[32];
  const float* fu_W2 = (const float*)d_in[33];
  const float* fu_b2 = (const float*)d_in[34];
  const float* rp_W1 = (const float*)d_in[35];
  const float* rp_b1 = (const float*)d_in[36];
  const float* rp_W2 = (const float*)d_in[37];
  const float* rp_b2 = (const float*)d_in[38];
  const float* fu_W3 = (const float*)d_in[39];
  const float* fu_b3 = (const float*)d_in[40];
  const float* rp_W3 = (const float*)d_in[41];
  const float* rp_b3 = (const float*)d_in[42];

  const int NU = in_sizes[6] / D;  // 10000 users
  const int B = in_sizes[0];       // 2048

  float* ws = (float*)d_ws;
  float* h_I_all = ws;               // NU*D
  float* op_ia = ws + (size_t)NU * D;
  float* op_ua = op_ia + 5 * D;

  k_op<<<10, 64, 0, stream>>>(opinion_emb, ia_Wg, ua_Wg, op_ia, op_ua);
  k_hIall<<<NU, 256, 0, stream>>>(C, Rm, user_emb, item_emb, ia_Wg, ia_bg,
                                  ia_Wa1, ia_ba1, ia_Wa2, ia_W, ia_b, op_ia,
                                  h_I_all);
  k_batch<<<B, 256, 0, stream>>>(user_idx, item_idx, Nn, Bm, Rm, user_emb,
                                 item_emb, sa_Wa1, sa_ba1, sa_Wa2, sa_W, sa_b,
                                 ua_Wg, ua_bg, ua_Wa1, ua_ba1, ua_Wa2, ua_W,
                                 ua_b, op_ua, fu_W1, fu_b1, fu_W2, fu_b2,
                                 fu_W3, fu_b3, rp_W1, rp_b1, rp_W2, rp_b2,
                                 rp_W3, rp_b3, h_I_all, (float*)d_out);
}

// Round 5
// 210.058 us; speedup vs baseline: 1.0560x; 1.0560x over previous
//
#include <hip/hip_runtime.h>

#define D 64
#define KP 50          // neighbors per row
#define NIT 10000      // R row stride
#define STR 68         // padded LDS row stride for tab kernels

// acc[dd] += sum_j Xr[j] * Wp[j*D + dd]   (Wp wave-uniform -> s_load + SGPR FMA)
__device__ inline void mm16(const float* Xr, const float* __restrict__ Wp,
                            float acc[16]) {
  for (int j4 = 0; j4 < D; j4 += 4) {
    float4 xv = *(const float4*)&Xr[j4];
    const float xr[4] = {xv.x, xv.y, xv.z, xv.w};
#pragma unroll
    for (int jj = 0; jj < 4; ++jj) {
#pragma unroll
      for (int dd = 0; dd < 16; ++dd)
        acc[dd] = fmaf(xr[jj], Wp[(j4 + jj) * D + dd], acc[dd]);
    }
  }
}

// y[d] = act(bias[d] + sum_{j<J} xin[j]*W[j][d]); 256 threads; part = 256 floats
template <int J, bool RELU>
__device__ inline void mv(const float* xin, float* y,
                          const float* __restrict__ W,
                          const float* __restrict__ bias, float* part) {
  const int w = threadIdx.x >> 6, d = threadIdx.x & 63;
  const int JW = J / 4;
  float p = 0.f;
  const float* xw = &xin[w * JW];
  const float* Wp = &W[(w * JW) * D + d];
  for (int j = 0; j < JW; ++j) {
    p = fmaf(xw[j], *Wp, p);
    Wp += D;
  }
  part[w * D + d] = p;
  __syncthreads();
  if (threadIdx.x < D) {
    float s = bias[d] + part[d] + part[D + d] + part[2 * D + d] +
              part[3 * D + d];
    y[d] = RELU ? fmaxf(s, 0.f) : s;
  }
  __syncthreads();
}

// attention scores from XA rows (+init_att, relu, dot Wa2), softmax over k,
// then v[d] = sum_k a[k] * Xv[ix[k]][d].  All row reads coalesced from global.
__device__ inline void agg(const float* __restrict__ XA,
                           const float* __restrict__ Xv, const int* ix,
                           const float* ia_lds, const float* __restrict__ Wa2,
                           float* a, float* v, float* part) {
  const int t = threadIdx.x, lane = t & 63, kw = t >> 6;
  const float w2 = Wa2[lane];
  const float iav = ia_lds[lane];
  for (int k = kw; k < KP; k += 4) {
    float p = fmaxf(XA[(size_t)ix[k] * D + lane] + iav, 0.f) * w2;
#pragma unroll
    for (int o = 1; o < 64; o <<= 1) p += __shfl_xor(p, o, 64);
    if (lane == 0) a[k] = p;
  }
  __syncthreads();
  if (t < D) {
    float val = (lane < KP) ? a[lane] : -1e30f;
    float m = val;
#pragma unroll
    for (int o = 1; o < 64; o <<= 1) m = fmaxf(m, __shfl_xor(m, o, 64));
    float e = (lane < KP) ? __expf(val - m) : 0.f;
    float s = e;
#pragma unroll
    for (int o = 1; o < 64; o <<= 1) s += __shfl_xor(s, o, 64);
    if (lane < KP) a[lane] = e / s;
  }
  __syncthreads();
  float p = 0.f;
  for (int k = kw; k < KP; k += 4)
    p = fmaf(a[k], Xv[(size_t)ix[k] * D + lane], p);
  part[kw * D + lane] = p;
  __syncthreads();
  if (t < D) v[t] = part[t] + part[D + t] + part[2 * D + t] + part[3 * D + t];
  __syncthreads();
}

// ---- table 1: X5[g][r] = relu(emb[g] @ Wg_lo + op[r] + bg), op computed in-block
__global__ __launch_bounds__(256) void k_tab_gate(
    const float* __restrict__ emb, const float* __restrict__ opinion_emb,
    const float* __restrict__ Wg, const float* __restrict__ bg,
    float* __restrict__ X5, int nrows) {
  __shared__ float X[64 * STR];
  __shared__ float opbg[5][D];
  const int t = threadIdx.x, lane = t & 63, kw = t >> 6;
  const int g0 = blockIdx.x * 64;
  for (int r = kw; r < 5; r += 4) {
    float acc = bg[lane];
    for (int j = 0; j < D; ++j)
      acc = fmaf(opinion_emb[r * D + j], Wg[(D + j) * D + lane], acc);
    opbg[r][lane] = acc;
  }
  for (int k = kw; k < 64; k += 4) {
    int g = g0 + k;
    if (g >= nrows) g = nrows - 1;
    X[k * STR + lane] = emb[g * D + lane];
  }
  __syncthreads();
  const int dwu = __builtin_amdgcn_readfirstlane(kw << 4);
  float acc[16];
#pragma unroll
  for (int dd = 0; dd < 16; ++dd) acc[dd] = 0.f;
  mm16(&X[lane * STR], &Wg[dwu], acc);
  __syncthreads();
#pragma unroll
  for (int dd4 = 0; dd4 < 16; dd4 += 4)
    *(float4*)&X[lane * STR + dwu + dd4] =
        make_float4(acc[dd4], acc[dd4 + 1], acc[dd4 + 2], acc[dd4 + 3]);
  __syncthreads();
  for (int k = kw; k < 64; k += 4) {
    int g = g0 + k;
    if (g >= nrows) continue;
    float base = X[k * STR + lane];
#pragma unroll
    for (int r = 0; r < 5; ++r)
      X5[((size_t)g * 5 + r) * D + lane] = fmaxf(base + opbg[r][lane], 0.f);
  }
}

// ---- table 2: Y[g] = Xin[g] @ W_lo   (W = first 64 rows of a 128x64 or 64x64)
__global__ __launch_bounds__(256) void k_tab_mm(const float* __restrict__ Xin,
                                                const float* __restrict__ W,
                                                float* __restrict__ Y,
                                                int nrows) {
  __shared__ float X[64 * STR];
  const int t = threadIdx.x, lane = t & 63, kw = t >> 6;
  const int g0 = blockIdx.x * 64;
  for (int k = kw; k < 64; k += 4) {
    int g = g0 + k;
    if (g >= nrows) g = nrows - 1;
    X[k * STR + lane] = Xin[(size_t)g * D + lane];
  }
  __syncthreads();
  const int dwu = __builtin_amdgcn_readfirstlane(kw << 4);
  float acc[16];
#pragma unroll
  for (int dd = 0; dd < 16; ++dd) acc[dd] = 0.f;
  mm16(&X[lane * STR], &W[dwu], acc);
  __syncthreads();
#pragma unroll
  for (int dd4 = 0; dd4 < 16; dd4 += 4)
    *(float4*)&X[lane * STR + dwu + dd4] =
        make_float4(acc[dd4], acc[dd4 + 1], acc[dd4 + 2], acc[dd4 + 3]);
  __syncthreads();
  for (int k = kw; k < 64; k += 4) {
    int g = g0 + k;
    if (g >= nrows) continue;
    Y[(size_t)g * D + lane] = X[k * STR + lane];
  }
}

// ---- kernel: h_I_all row per user (no matmuls, table gathers only) -------------
struct SMH {
  float ctx[D], ia[D], a[D], v[D], part[4 * D];
  int ix[KP];
};

__global__ __launch_bounds__(256, 8) void k_hIall(
    const int* __restrict__ C, const int* __restrict__ Rm,
    const float* __restrict__ user_emb, const float* __restrict__ Wa1,
    const float* __restrict__ ba1, const float* __restrict__ Wa2,
    const float* __restrict__ Wf, const float* __restrict__ bf,
    const float* __restrict__ X5, const float* __restrict__ XA5,
    float* __restrict__ h_I_all) {
  __shared__ SMH sm;
  const int u = blockIdx.x, t = threadIdx.x;
  if (t < KP) {
    int c = C[u * KP + t];
    sm.ix[t] = c * 5 + Rm[(size_t)u * NIT + c];  // HBM-latency gather
  }
  if (t < D) sm.ctx[t] = user_emb[u * D + t];
  __syncthreads();
  mv<D, false>(sm.ctx, sm.ia, &Wa1[D * D], ba1, sm.part);  // ia = ba1 + ctx@Wa1hi
  agg(XA5, X5, sm.ix, sm.ia, Wa2, sm.a, sm.v, sm.part);
  mv<D, true>(sm.v, &h_I_all[(size_t)u * D], Wf, bf, sm.part);
}

// ---- kernel: per-batch h_S + z + fu/rp MLPs → output ---------------------------
struct SMB {
  float ctx[D], ia[D], a[D], v[D], hS[D], z[D], cat[2 * D], buf[D],
      part[4 * D];
  int ix[KP], ix2[KP];
};

__global__ __launch_bounds__(256, 8) void k_batch(
    const int* __restrict__ user_idx, const int* __restrict__ item_idx,
    const int* __restrict__ Nn, const int* __restrict__ Bm,
    const int* __restrict__ Rm, const float* __restrict__ user_emb,
    const float* __restrict__ item_emb, const float* __restrict__ sa_Wa1,
    const float* __restrict__ sa_ba1, const float* __restrict__ sa_Wa2,
    const float* __restrict__ sa_W, const float* __restrict__ sa_b,
    const float* __restrict__ ua_Wa1, const float* __restrict__ ua_ba1,
    const float* __restrict__ ua_Wa2, const float* __restrict__ ua_W,
    const float* __restrict__ ua_b, const float* __restrict__ fu_W1,
    const float* __restrict__ fu_b1, const float* __restrict__ fu_W2,
    const float* __restrict__ fu_b2, const float* __restrict__ fu_W3,
    const float* __restrict__ fu_b3, const float* __restrict__ rp_W1,
    const float* __restrict__ rp_b1, const float* __restrict__ rp_W2,
    const float* __restrict__ rp_b2, const float* __restrict__ rp_W3,
    const float* __restrict__ rp_b3, const float* __restrict__ h_I_all,
    const float* __restrict__ HA, const float* __restrict__ F5,
    const float* __restrict__ FA5, float* __restrict__ out) {
  __shared__ SMB sm;
  const int b = blockIdx.x, t = threadIdx.x;
  const int u = user_idx[b], it = item_idx[b];
  if (t < KP) {
    sm.ix[t] = Nn[u * KP + t];
    int bn = Bm[it * KP + t];
    sm.ix2[t] = bn * 5 + Rm[(size_t)bn * NIT + it];  // prefetch for phase Z
  }
  if (t < D) sm.ctx[t] = user_emb[u * D + t];
  __syncthreads();
  // ---- phase S: social aggregation (rows = h_I_all / HA) ----
  mv<D, false>(sm.ctx, sm.ia, &sa_Wa1[D * D], sa_ba1, sm.part);
  agg(HA, h_I_all, sm.ix, sm.ia, sa_Wa2, sm.a, sm.v, sm.part);
  mv<D, true>(sm.v, sm.hS, sa_W, sa_b, sm.part);
  // ---- phase Z: item-side aggregation (rows = FA5 / F5) ----
  if (t < D) sm.ctx[t] = item_emb[it * D + t];
  __syncthreads();
  mv<D, false>(sm.ctx, sm.ia, &ua_Wa1[D * D], ua_ba1, sm.part);
  agg(FA5, F5, sm.ix2, sm.ia, ua_Wa2, sm.a, sm.v, sm.part);
  mv<D, true>(sm.v, sm.z, ua_W, ua_b, sm.part);
  // ---- fu MLP on concat(h_I_all[u], h_S) ----
  if (t < D) {
    sm.cat[t] = h_I_all[(size_t)u * D + t];
    sm.cat[D + t] = sm.hS[t];
  }
  __syncthreads();
  mv<2 * D, true>(sm.cat, sm.buf, fu_W1, fu_b1, sm.part);
  mv<D, true>(sm.buf, sm.v, fu_W2, fu_b2, sm.part);
  mv<D, true>(sm.v, sm.buf, fu_W3, fu_b3, sm.part);
  // ---- rp MLP on concat(h, z) ----
  if (t < D) {
    sm.cat[t] = sm.buf[t];
    sm.cat[D + t] = sm.z[t];
  }
  __syncthreads();
  mv<2 * D, true>(sm.cat, sm.buf, rp_W1, rp_b1, sm.part);
  mv<D, true>(sm.buf, sm.v, rp_W2, rp_b2, sm.part);
  if (t < D) {
    float p = sm.v[t] * rp_W3[t];
#pragma unroll
    for (int o = 1; o < 64; o <<= 1) p += __shfl_xor(p, o, 64);
    if (t == 0) out[b] = p + rp_b3[0];
  }
}

extern "C" void kernel_launch(void* const* d_in, const int* in_sizes, int n_in,
                              void* d_out, int out_size, void* d_ws,
                              size_t ws_size, hipStream_t stream) {
  const int* user_idx = (const int*)d_in[0];
  const int* item_idx = (const int*)d_in[1];
  const int* C = (const int*)d_in[2];
  const int* Nn = (const int*)d_in[3];
  const int* Bm = (const int*)d_in[4];
  const int* Rm = (const int*)d_in[5];
  const float* user_emb = (const float*)d_in[6];
  const float* item_emb = (const float*)d_in[7];
  const float* opinion_emb = (const float*)d_in[8];
  const float* ia_Wg = (const float*)d_in[9];
  const float* ia_bg = (const float*)d_in[10];
  const float* ua_Wg = (const float*)d_in[11];
  const float* ua_bg = (const float*)d_in[12];
  const float* ia_Wa1 = (const float*)d_in[13];
  const float* ia_ba1 = (const float*)d_in[14];
  const float* ia_Wa2 = (const float*)d_in[15];
  const float* ia_W = (const float*)d_in[17];
  const float* ia_b = (const float*)d_in[18];
  const float* sa_Wa1 = (const float*)d_in[19];
  const float* sa_ba1 = (const float*)d_in[20];
  const float* sa_Wa2 = (const float*)d_in[21];
  const float* sa_W = (const float*)d_in[23];
  const float* sa_b = (const float*)d_in[24];
  const float* ua_Wa1 = (const float*)d_in[25];
  const float* ua_ba1 = (const float*)d_in[26];
  const float* ua_Wa2 = (const float*)d_in[27];
  const float* ua_W = (const float*)d_in[29];
  const float* ua_b = (const float*)d_in[30];
  const float* fu_W1 = (const float*)d_in[31];
  const float* fu_b1 = (const float*)d_in[32];
  const float* fu_W2 = (const float*)d_in[33];
  const float* fu_b2 = (const float*)d_in[34];
  const float* rp_W1 = (const float*)d_in[35];
  const float* rp_b1 = (const float*)d_in[36];
  const float* rp_W2 = (const float*)d_in[37];
  const float* rp_b2 = (const float*)d_in[38];
  const float* fu_W3 = (const float*)d_in[39];
  const float* fu_b3 = (const float*)d_in[40];
  const float* rp_W3 = (const float*)d_in[41];
  const float* rp_b3 = (const float*)d_in[42];

  const int NU = in_sizes[6] / D;  // 10000 users
  const int B = in_sizes[0];       // 2048

  float* ws = (float*)d_ws;
  float* X5 = ws;                          // NU*5*D  gate outputs (item,r)
  float* XA5 = X5 + (size_t)NU * 5 * D;    // NU*5*D  X5 @ ia_Wa1_lo
  float* F5 = XA5 + (size_t)NU * 5 * D;    // NU*5*D  gate outputs (user,r)
  float* FA5 = F5 + (size_t)NU * 5 * D;    // NU*5*D  F5 @ ua_Wa1_lo
  float* hI = FA5 + (size_t)NU * 5 * D;    // NU*D
  float* HA = hI + (size_t)NU * D;         // NU*D    hI @ sa_Wa1_lo

  const int nb = (NU + 63) / 64;       // 157
  const int nb5 = (NU * 5 + 63) / 64;  // 782

  k_tab_gate<<<nb, 256, 0, stream>>>(item_emb, opinion_emb, ia_Wg, ia_bg, X5, NU);
  k_tab_gate<<<nb, 256, 0, stream>>>(user_emb, opinion_emb, ua_Wg, ua_bg, F5, NU);
  k_tab_mm<<<nb5, 256, 0, stream>>>(X5, ia_Wa1, XA5, NU * 5);
  k_tab_mm<<<nb5, 256, 0, stream>>>(F5, ua_Wa1, FA5, NU * 5);
  k_hIall<<<NU, 256, 0, stream>>>(C, Rm, user_emb, ia_Wa1, ia_ba1, ia_Wa2,
                                  ia_W, ia_b, X5, XA5, hI);
  k_tab_mm<<<nb, 256, 0, stream>>>(hI, sa_Wa1, HA, NU);
  k_batch<<<B, 256, 0, stream>>>(user_idx, item_idx, Nn, Bm, Rm, user_emb,
                                 item_emb, sa_Wa1, sa_ba1, sa_Wa2, sa_W, sa_b,
                                 ua_Wa1, ua_ba1, ua_Wa2, ua_W, ua_b, fu_W1,
                                 fu_b1, fu_W2, fu_b2, fu_W3, fu_b3, rp_W1,
                                 rp_b1, rp_W2, rp_b2, rp_W3, rp_b3, hI, HA, F5,
                                 FA5, (float*)d_out);
}

// Round 6
// 134.257 us; speedup vs baseline: 1.6523x; 1.5646x over previous
//
#include <hip/hip_runtime.h>

#define D 64
#define KP 50          // neighbors per row
#define NIT 10000      // R row stride
#define STR 68         // padded LDS row stride (tab kernels only)

// ---------------- wave-level helpers (no LDS, no barriers) ----------------------

// score = sum_d relu(xa[d] + ia[d]) * w2[d]; xa per-lane row, ia/w2 uniform (s_load)
__device__ inline float score_row(const float* xa, const float* __restrict__ ia,
                                  const float* __restrict__ w2) {
  float p = 0.f;
#pragma unroll 16
  for (int j = 0; j < D; ++j) p = fmaf(fmaxf(xa[j] + ia[j], 0.f), w2[j], p);
  return p;
}

// masked softmax over lanes 0..KP-1; lanes >= KP return 0
__device__ inline float softmax50(float val, int lane) {
  val = (lane < KP) ? val : -1e30f;
  float m = val;
#pragma unroll
  for (int o = 1; o < 64; o <<= 1) m = fmaxf(m, __shfl_xor(m, o, 64));
  float e = (lane < KP) ? __expf(val - m) : 0.f;
  float s = e;
#pragma unroll
  for (int o = 1; o < 64; o <<= 1) s += __shfl_xor(s, o, 64);
  return e / s;
}

// v[lane] = sum_k a_k * T[ix_k][lane]   (a, ix live in lane k; rows coalesced)
__device__ inline float wsum_rows(float a, int ix, const float* __restrict__ T,
                                  int lane) {
  float v = 0.f;
#pragma unroll 10
  for (int k = 0; k < KP; ++k) {
    int ixk = __builtin_amdgcn_readfirstlane(__shfl(ix, k, 64));
    float ak = __shfl(a, k, 64);
    v = fmaf(ak, T[(size_t)ixk * D + lane], v);
  }
  return v;
}

// y[lane] = act(bias[lane] + sum_j vin_j * W[j][lane]); vin broadcast via readlane
template <bool RELU>
__device__ inline float mv64b(float vin, const float* __restrict__ W,
                              const float* __restrict__ bias, int lane) {
  float acc = bias[lane];
#pragma unroll 8
  for (int j = 0; j < D; ++j)
    acc = fmaf(__shfl(vin, j, 64), W[j * D + lane], acc);
  return RELU ? fmaxf(acc, 0.f) : acc;
}

// y[lane] = relu(bias[lane] + sum_j cat(lo,hi)_j * W[j][lane]), J = 128
__device__ inline float mv128b(float lo, float hi, const float* __restrict__ W,
                               const float* __restrict__ bias, int lane) {
  float acc = bias[lane];
#pragma unroll 8
  for (int j = 0; j < D; ++j)
    acc = fmaf(__shfl(lo, j, 64), W[j * D + lane], acc);
#pragma unroll 8
  for (int j = 0; j < D; ++j)
    acc = fmaf(__shfl(hi, j, 64), W[(D + j) * D + lane], acc);
  return fmaxf(acc, 0.f);
}

// ---------------- dense table kernels (LDS tile + SGPR-W matmul) ----------------

// acc[dd] += sum_j Xr[j] * Wp[j*D + dd]   (Wp wave-uniform -> s_load)
__device__ inline void mm16(const float* Xr, const float* __restrict__ Wp,
                            float acc[16]) {
  for (int j4 = 0; j4 < D; j4 += 4) {
    float4 xv = *(const float4*)&Xr[j4];
    const float xr[4] = {xv.x, xv.y, xv.z, xv.w};
#pragma unroll
    for (int jj = 0; jj < 4; ++jj) {
#pragma unroll
      for (int dd = 0; dd < 16; ++dd)
        acc[dd] = fmaf(xr[jj], Wp[(j4 + jj) * D + dd], acc[dd]);
    }
  }
}

// gate tables: X5[g][r] = relu(emb[g] @ Wg_lo + op_emb[r] @ Wg_hi + bg)
// blockIdx < nb: (item_emb, ia_*) -> X5 ; else (user_emb, ua_*) -> F5
__global__ __launch_bounds__(256) void k_tab_gate(
    const float* __restrict__ item_emb, const float* __restrict__ user_emb,
    const float* __restrict__ op_emb, const float* __restrict__ ia_Wg,
    const float* __restrict__ ia_bg, const float* __restrict__ ua_Wg,
    const float* __restrict__ ua_bg, float* __restrict__ X5,
    float* __restrict__ F5, int nrows, int nb) {
  __shared__ float X[64 * STR];
  __shared__ float opbg[5][D];
  const bool second = (int)blockIdx.x >= nb;
  const float* emb = second ? user_emb : item_emb;
  const float* Wg = second ? ua_Wg : ia_Wg;
  const float* bg = second ? ua_bg : ia_bg;
  float* dst = second ? F5 : X5;
  const int blk = second ? blockIdx.x - nb : blockIdx.x;
  const int t = threadIdx.x, lane = t & 63, kw = t >> 6;
  const int g0 = blk * 64;
  for (int r = kw; r < 5; r += 4) {
    float acc = bg[lane];
    for (int j = 0; j < D; ++j)
      acc = fmaf(op_emb[r * D + j], Wg[(D + j) * D + lane], acc);
    opbg[r][lane] = acc;
  }
  for (int k = kw; k < 64; k += 4) {
    int g = g0 + k;
    if (g >= nrows) g = nrows - 1;
    X[k * STR + lane] = emb[(size_t)g * D + lane];
  }
  __syncthreads();
  const int dwu = __builtin_amdgcn_readfirstlane(kw << 4);
  float acc[16];
#pragma unroll
  for (int dd = 0; dd < 16; ++dd) acc[dd] = 0.f;
  mm16(&X[lane * STR], &Wg[dwu], acc);
  __syncthreads();
#pragma unroll
  for (int dd4 = 0; dd4 < 16; dd4 += 4)
    *(float4*)&X[lane * STR + dwu + dd4] =
        make_float4(acc[dd4], acc[dd4 + 1], acc[dd4 + 2], acc[dd4 + 3]);
  __syncthreads();
  for (int k = kw; k < 64; k += 4) {
    int g = g0 + k;
    if (g >= nrows) continue;
    float base = X[k * STR + lane];
#pragma unroll
    for (int r = 0; r < 5; ++r)
      dst[((size_t)g * 5 + r) * D + lane] = fmaxf(base + opbg[r][lane], 0.f);
  }
}

// five dense 64-wide GEMMs in one launch: dst = src @ W (+ bias)
struct Job {
  const float* src;
  const float* W;
  const float* bias;
  float* dst;
  int nrows;
};
struct Jobs5 {
  Job j[5];
  int off[5];  // starting blockIdx of each job
};

__global__ __launch_bounds__(256) void k_tab_mm5(Jobs5 J) {
  __shared__ float X[64 * STR];
  int bid = blockIdx.x;
  int s = 0;
  while (s < 4 && bid >= J.off[s + 1]) ++s;
  const Job jb = J.j[s];
  const int blk = bid - J.off[s];
  const int t = threadIdx.x, lane = t & 63, kw = t >> 6;
  const int g0 = blk * 64;
  for (int k = kw; k < 64; k += 4) {
    int g = g0 + k;
    if (g >= jb.nrows) g = jb.nrows - 1;
    X[k * STR + lane] = jb.src[(size_t)g * D + lane];
  }
  __syncthreads();
  const int dwu = __builtin_amdgcn_readfirstlane(kw << 4);
  float acc[16];
#pragma unroll
  for (int dd = 0; dd < 16; ++dd) acc[dd] = 0.f;
  mm16(&X[lane * STR], &jb.W[dwu], acc);
  __syncthreads();
#pragma unroll
  for (int dd4 = 0; dd4 < 16; dd4 += 4)
    *(float4*)&X[lane * STR + dwu + dd4] =
        make_float4(acc[dd4], acc[dd4 + 1], acc[dd4 + 2], acc[dd4 + 3]);
  __syncthreads();
  const float bv = jb.bias ? jb.bias[lane] : 0.f;
  for (int k = kw; k < 64; k += 4) {
    int g = g0 + k;
    if (g >= jb.nrows) continue;
    jb.dst[(size_t)g * D + lane] = X[k * STR + lane] + bv;
  }
}

// ---------------- h_I_all: one wave per user, zero barriers ---------------------
__global__ __launch_bounds__(256, 8) void k_hIall(
    const int* __restrict__ C, const int* __restrict__ Rm,
    const float* __restrict__ X5, const float* __restrict__ XA5,
    const float* __restrict__ IAu, const float* __restrict__ ia_Wa2,
    const float* __restrict__ ia_W, const float* __restrict__ ia_b,
    const float* __restrict__ sa_Wa1, float* __restrict__ hI,
    float* __restrict__ HA) {
  const int lane = threadIdx.x & 63;
  const int u =
      __builtin_amdgcn_readfirstlane(blockIdx.x * 4 + (threadIdx.x >> 6));
  const int kk = lane < KP ? lane : KP - 1;
  const int c = C[u * KP + kk];
  const int ix = c * 5 + Rm[(size_t)u * NIT + c];
  float sc = score_row(XA5 + (size_t)ix * D, IAu + (size_t)u * D, ia_Wa2);
  float a = softmax50(sc, lane);
  float v = wsum_rows(a, ix, X5, lane);
  float h = mv64b<true>(v, ia_W, ia_b, lane);
  hI[(size_t)u * D + lane] = h;
  float ha = 0.f;
#pragma unroll 8
  for (int j = 0; j < D; ++j)
    ha = fmaf(__shfl(h, j, 64), sa_Wa1[j * D + lane], ha);
  HA[(size_t)u * D + lane] = ha;
}

// ---------------- batch: one wave per row, zero barriers ------------------------
__global__ __launch_bounds__(256, 8) void k_batch(
    const int* __restrict__ user_idx, const int* __restrict__ item_idx,
    const int* __restrict__ Nn, const int* __restrict__ Bm,
    const int* __restrict__ Rm, const float* __restrict__ hIa,
    const float* __restrict__ HA, const float* __restrict__ F5,
    const float* __restrict__ FA5, const float* __restrict__ SAu,
    const float* __restrict__ UAt, const float* __restrict__ sa_Wa2,
    const float* __restrict__ sa_W, const float* __restrict__ sa_b,
    const float* __restrict__ ua_Wa2, const float* __restrict__ ua_W,
    const float* __restrict__ ua_b, const float* __restrict__ fu_W1,
    const float* __restrict__ fu_b1, const float* __restrict__ fu_W2,
    const float* __restrict__ fu_b2, const float* __restrict__ fu_W3,
    const float* __restrict__ fu_b3, const float* __restrict__ rp_W1,
    const float* __restrict__ rp_b1, const float* __restrict__ rp_W2,
    const float* __restrict__ rp_b2, const float* __restrict__ rp_W3,
    const float* __restrict__ rp_b3, float* __restrict__ out) {
  const int lane = threadIdx.x & 63;
  const int b =
      __builtin_amdgcn_readfirstlane(blockIdx.x * 4 + (threadIdx.x >> 6));
  const int u = __builtin_amdgcn_readfirstlane(user_idx[b]);
  const int it = __builtin_amdgcn_readfirstlane(item_idx[b]);
  const int kk = lane < KP ? lane : KP - 1;
  const int nix = Nn[u * KP + kk];               // social neighbor ids
  const int bn = Bm[it * KP + kk];               // item-side user ids
  const int ix2 = bn * 5 + Rm[(size_t)bn * NIT + it];
  const float hIu = hIa[(size_t)u * D + lane];
  // ---- phase S: social aggregation over (HA, hI) rows ----
  float sc = score_row(HA + (size_t)nix * D, SAu + (size_t)u * D, sa_Wa2);
  float a = softmax50(sc, lane);
  float v = wsum_rows(a, nix, hIa, lane);
  float hS = mv64b<true>(v, sa_W, sa_b, lane);
  // ---- phase Z: item-side aggregation over (FA5, F5) rows ----
  float sc2 = score_row(FA5 + (size_t)ix2 * D, UAt + (size_t)it * D, ua_Wa2);
  float a2 = softmax50(sc2, lane);
  float v2 = wsum_rows(a2, ix2, F5, lane);
  float z = mv64b<true>(v2, ua_W, ua_b, lane);
  // ---- fu MLP on concat(hI[u], hS) ----
  float h = mv128b(hIu, hS, fu_W1, fu_b1, lane);
  h = mv64b<true>(h, fu_W2, fu_b2, lane);
  h = mv64b<true>(h, fu_W3, fu_b3, lane);
  // ---- rp MLP on concat(h, z) ----
  float g = mv128b(h, z, rp_W1, rp_b1, lane);
  g = mv64b<true>(g, rp_W2, rp_b2, lane);
  float p = g * rp_W3[lane];
#pragma unroll
  for (int o = 1; o < 64; o <<= 1) p += __shfl_xor(p, o, 64);
  if (lane == 0) out[b] = p + rp_b3[0];
}

extern "C" void kernel_launch(void* const* d_in, const int* in_sizes, int n_in,
                              void* d_out, int out_size, void* d_ws,
                              size_t ws_size, hipStream_t stream) {
  const int* user_idx = (const int*)d_in[0];
  const int* item_idx = (const int*)d_in[1];
  const int* C = (const int*)d_in[2];
  const int* Nn = (const int*)d_in[3];
  const int* Bm = (const int*)d_in[4];
  const int* Rm = (const int*)d_in[5];
  const float* user_emb = (const float*)d_in[6];
  const float* item_emb = (const float*)d_in[7];
  const float* opinion_emb = (const float*)d_in[8];
  const float* ia_Wg = (const float*)d_in[9];
  const float* ia_bg = (const float*)d_in[10];
  const float* ua_Wg = (const float*)d_in[11];
  const float* ua_bg = (const float*)d_in[12];
  const float* ia_Wa1 = (const float*)d_in[13];
  const float* ia_ba1 = (const float*)d_in[14];
  const float* ia_Wa2 = (const float*)d_in[15];
  const float* ia_W = (const float*)d_in[17];
  const float* ia_b = (const float*)d_in[18];
  const float* sa_Wa1 = (const float*)d_in[19];
  const float* sa_ba1 = (const float*)d_in[20];
  const float* sa_Wa2 = (const float*)d_in[21];
  const float* sa_W = (const float*)d_in[23];
  const float* sa_b = (const float*)d_in[24];
  const float* ua_Wa1 = (const float*)d_in[25];
  const float* ua_ba1 = (const float*)d_in[26];
  const float* ua_Wa2 = (const float*)d_in[27];
  const float* ua_W = (const float*)d_in[29];
  const float* ua_b = (const float*)d_in[30];
  const float* fu_W1 = (const float*)d_in[31];
  const float* fu_b1 = (const float*)d_in[32];
  const float* fu_W2 = (const float*)d_in[33];
  const float* fu_b2 = (const float*)d_in[34];
  const float* rp_W1 = (const float*)d_in[35];
  const float* rp_b1 = (const float*)d_in[36];
  const float* rp_W2 = (const float*)d_in[37];
  const float* rp_b2 = (const float*)d_in[38];
  const float* fu_W3 = (const float*)d_in[39];
  const float* fu_b3 = (const float*)d_in[40];
  const float* rp_W3 = (const float*)d_in[41];
  const float* rp_b3 = (const float*)d_in[42];

  const int NU = in_sizes[6] / D;  // 10000 users
  const int B = in_sizes[0];       // 2048

  float* ws = (float*)d_ws;
  float* X5 = ws;                        // NU*5*D
  float* XA5 = X5 + (size_t)NU * 5 * D;  // NU*5*D
  float* F5 = XA5 + (size_t)NU * 5 * D;  // NU*5*D
  float* FA5 = F5 + (size_t)NU * 5 * D;  // NU*5*D
  float* hI = FA5 + (size_t)NU * 5 * D;  // NU*D
  float* HA = hI + (size_t)NU * D;       // NU*D
  float* IAu = HA + (size_t)NU * D;      // NU*D
  float* SAu = IAu + (size_t)NU * D;     // NU*D
  float* UAt = SAu + (size_t)NU * D;     // NU*D

  const int nb = (NU + 63) / 64;        // 157
  const int nb5 = (NU * 5 + 63) / 64;   // 782

  k_tab_gate<<<2 * nb, 256, 0, stream>>>(item_emb, user_emb, opinion_emb,
                                         ia_Wg, ia_bg, ua_Wg, ua_bg, X5, F5,
                                         NU, nb);
  Jobs5 J;
  J.j[0] = {X5, ia_Wa1, nullptr, XA5, NU * 5};
  J.j[1] = {F5, ua_Wa1, nullptr, FA5, NU * 5};
  J.j[2] = {user_emb, &ia_Wa1[D * D], ia_ba1, IAu, NU};
  J.j[3] = {user_emb, &sa_Wa1[D * D], sa_ba1, SAu, NU};
  J.j[4] = {item_emb, &ua_Wa1[D * D], ua_ba1, UAt, NU};
  J.off[0] = 0;
  J.off[1] = nb5;
  J.off[2] = 2 * nb5;
  J.off[3] = 2 * nb5 + nb;
  J.off[4] = 2 * nb5 + 2 * nb;
  const int total_mm = 2 * nb5 + 3 * nb;
  k_tab_mm5<<<total_mm, 256, 0, stream>>>(J);
  k_hIall<<<NU / 4, 256, 0, stream>>>(C, Rm, X5, XA5, IAu, ia_Wa2, ia_W, ia_b,
                                      sa_Wa1, hI, HA);
  k_batch<<<B / 4, 256, 0, stream>>>(user_idx, item_idx, Nn, Bm, Rm, hI, HA,
                                     F5, FA5, SAu, UAt, sa_Wa2, sa_W, sa_b,
                                     ua_Wa2, ua_W, ua_b, fu_W1, fu_b1, fu_W2,
                                     fu_b2, fu_W3, fu_b3, rp_W1, rp_b1, rp_W2,
                                     rp_b2, rp_W3, rp_b3, (float*)d_out);
}